// Round 1
// baseline (7201.837 us; speedup 1.0000x reference)
//
#include <hip/hip_runtime.h>
#include <hip/hip_bf16.h>

#define UNITS 32

__device__ __forceinline__ float sigmoidf_(float x) {
    return 1.0f / (1.0f + __expf(-x));
}
__device__ __forceinline__ float tanhf_(float x) {
    // tanh(x) = 1 - 2/(exp(2x)+1); saturates correctly at +-inf
    float e = __expf(2.0f * x);
    return 1.0f - 2.0f / (e + 1.0f);
}
__device__ __forceinline__ float f4c(const float4& v, int q) {
    return q == 0 ? v.x : q == 1 ? v.y : q == 2 ? v.z : v.w;
}

// ---------------------------------------------------------------------------
// Kernel 1: G[node, 0..95] = h[node] @ Wih.T + bih   (per-node input gates)
// ---------------------------------------------------------------------------
__global__ __launch_bounds__(256) void precompute_gi(
    const float* __restrict__ h, const float* __restrict__ Wih,
    const float* __restrict__ bih, float* __restrict__ G, int n1)
{
    int node = blockIdx.x * 256 + threadIdx.x;
    if (node >= n1) return;
    float x[32];
    const float4* hx = (const float4*)(h + (size_t)node * 32);
#pragma unroll
    for (int c = 0; c < 8; ++c) {
        float4 v = hx[c];
        x[c*4+0] = v.x; x[c*4+1] = v.y; x[c*4+2] = v.z; x[c*4+3] = v.w;
    }
    float* grow = G + (size_t)node * 96;
#pragma unroll
    for (int jb = 0; jb < 24; ++jb) {
        float acc[4];
#pragma unroll
        for (int q = 0; q < 4; ++q) {
            int j = jb * 4 + q;
            float a = bih[j];
#pragma unroll
            for (int i = 0; i < 32; ++i)
                a += x[i] * Wih[j * 32 + i];
            acc[q] = a;
        }
        *(float4*)(grow + jb * 4) = make_float4(acc[0], acc[1], acc[2], acc[3]);
    }
}

// ---------------------------------------------------------------------------
// Kernel 2: per-edge GRU (K steps) + scatter-add of every step's h into hk
//   USE_G: gi gathered from precomputed G; else computed from gathered h row.
// ---------------------------------------------------------------------------
template <int K, bool USE_G>
__global__ __launch_bounds__(256) void gru_edges(
    const int* __restrict__ idx, int nE,
    const float* __restrict__ G, const float* __restrict__ h,
    const float* __restrict__ Wih, const float* __restrict__ Whh,
    const float* __restrict__ bih, const float* __restrict__ bhh,
    float* __restrict__ hk)
{
    int e = blockIdx.x * 256 + threadIdx.x;
    if (e >= nE) return;

    float hv[32];
#pragma unroll
    for (int t = 0; t < K; ++t) {
        int node = idx[(size_t)e * K + t];
        const float* grow = G + (size_t)node * 96;

        float x[32];
        if (!USE_G) {
            const float4* hx = (const float4*)(h + (size_t)node * 32);
#pragma unroll
            for (int c = 0; c < 8; ++c) {
                float4 v = hx[c];
                x[c*4+0] = v.x; x[c*4+1] = v.y; x[c*4+2] = v.z; x[c*4+3] = v.w;
            }
        }

        float hn_[32];
#pragma unroll
        for (int jb = 0; jb < 8; ++jb) {
            float4 gr4, gz4, gn4;
            if (USE_G) {
                gr4 = *(const float4*)(grow + jb * 4);
                gz4 = *(const float4*)(grow + 32 + jb * 4);
                gn4 = *(const float4*)(grow + 64 + jb * 4);
            }
#pragma unroll
            for (int q = 0; q < 4; ++q) {
                int j = jb * 4 + q;
                float ir, iz, in_;
                if (USE_G) {
                    ir = f4c(gr4, q); iz = f4c(gz4, q); in_ = f4c(gn4, q);
                } else {
                    ir = bih[j]; iz = bih[32 + j]; in_ = bih[64 + j];
#pragma unroll
                    for (int i = 0; i < 32; ++i) {
                        ir  += x[i] * Wih[j * 32 + i];
                        iz  += x[i] * Wih[(32 + j) * 32 + i];
                        in_ += x[i] * Wih[(64 + j) * 32 + i];
                    }
                }
                float hr = bhh[j], hz = bhh[32 + j], hn2 = bhh[64 + j];
                if (t > 0) {
#pragma unroll
                    for (int i = 0; i < 32; ++i) {
                        hr  += hv[i] * Whh[j * 32 + i];
                        hz  += hv[i] * Whh[(32 + j) * 32 + i];
                        hn2 += hv[i] * Whh[(64 + j) * 32 + i];
                    }
                }
                float r = sigmoidf_(ir + hr);
                float z = sigmoidf_(iz + hz);
                float n = tanhf_(in_ + r * hn2);
                hn_[j] = (t > 0) ? ((1.0f - z) * n + z * hv[j]) : (1.0f - z) * n;
            }
        }
        float* dst = hk + (size_t)node * 32;
#pragma unroll
        for (int j = 0; j < 32; ++j) {
            hv[j] = hn_[j];
            atomicAdd(dst + j, hn_[j]);
        }
    }
}

// ---------------------------------------------------------------------------
// Kernel 3: out = tanh([h|hk2|hk3|hk4] @ W1.T + b1) @ W2.T + b2
// ---------------------------------------------------------------------------
__global__ __launch_bounds__(256) void mlp_out(
    const float* __restrict__ h, const float* __restrict__ hk, int n1,
    const float* __restrict__ W1, const float* __restrict__ b1,
    const float* __restrict__ W2, const float* __restrict__ b2,
    float* __restrict__ out)
{
    int node = blockIdx.x * 256 + threadIdx.x;
    if (node >= n1) return;

    float acc[32];
#pragma unroll
    for (int j = 0; j < 32; ++j) acc[j] = b1[j];

    const float* zsrc[4];
    zsrc[0] = h + (size_t)node * 32;
    zsrc[1] = hk + (size_t)node * 32;
    zsrc[2] = hk + (size_t)n1 * 32 + (size_t)node * 32;
    zsrc[3] = hk + (size_t)n1 * 64 + (size_t)node * 32;

#pragma unroll
    for (int m = 0; m < 4; ++m) {
        float zc[32];
        const float4* zp = (const float4*)zsrc[m];
#pragma unroll
        for (int c = 0; c < 8; ++c) {
            float4 v = zp[c];
            zc[c*4+0] = v.x; zc[c*4+1] = v.y; zc[c*4+2] = v.z; zc[c*4+3] = v.w;
        }
#pragma unroll
        for (int j = 0; j < 32; ++j) {
#pragma unroll
            for (int i = 0; i < 32; ++i)
                acc[j] += zc[i] * W1[j * 128 + m * 32 + i];
        }
    }
    float tv[32];
#pragma unroll
    for (int j = 0; j < 32; ++j) tv[j] = tanhf_(acc[j]);

    float* orow = out + (size_t)node * 32;
#pragma unroll
    for (int ob = 0; ob < 8; ++ob) {
        float o[4];
#pragma unroll
        for (int q = 0; q < 4; ++q) {
            int oj = ob * 4 + q;
            float a = b2[oj];
#pragma unroll
            for (int j = 0; j < 32; ++j)
                a += tv[j] * W2[oj * 32 + j];
            o[q] = a;
        }
        *(float4*)(orow + ob * 4) = make_float4(o[0], o[1], o[2], o[3]);
    }
}

// ---------------------------------------------------------------------------
extern "C" void kernel_launch(void* const* d_in, const int* in_sizes, int n_in,
                              void* d_out, int out_size, void* d_ws, size_t ws_size,
                              hipStream_t stream)
{
    const float* h    = (const float*)d_in[0];
    const int*   idx2 = (const int*)d_in[1];
    const int*   idx3 = (const int*)d_in[2];
    const int*   idx4 = (const int*)d_in[3];
    const float* Wih  = (const float*)d_in[4];
    const float* Whh  = (const float*)d_in[5];
    const float* bih  = (const float*)d_in[6];
    const float* bhh  = (const float*)d_in[7];
    const float* W1   = (const float*)d_in[8];
    const float* b1   = (const float*)d_in[9];
    const float* W2   = (const float*)d_in[10];
    const float* b2   = (const float*)d_in[11];
    float* out = (float*)d_out;

    int n1 = in_sizes[0] / 32;
    int n2 = in_sizes[1] / 2;
    int n3 = in_sizes[2] / 3;
    int n4 = in_sizes[3] / 4;

    // ws layout: [hk2|hk3|hk4] (n1*96 floats) then optionally [G] (n1*96 floats)
    float* hk = (float*)d_ws;
    size_t hkBytes = (size_t)n1 * 96 * sizeof(float);
    size_t gBytes  = (size_t)n1 * 96 * sizeof(float);
    bool useG = (ws_size >= hkBytes + gBytes);
    float* G = (float*)((char*)d_ws + hkBytes);

    hipMemsetAsync(d_ws, 0, hkBytes, stream);

    int blocksN1 = (n1 + 255) / 256;
    if (useG) {
        precompute_gi<<<blocksN1, 256, 0, stream>>>(h, Wih, bih, G, n1);
        gru_edges<2, true><<<(n2 + 255) / 256, 256, 0, stream>>>(
            idx2, n2, G, h, Wih, Whh, bih, bhh, hk);
        gru_edges<3, true><<<(n3 + 255) / 256, 256, 0, stream>>>(
            idx3, n3, G, h, Wih, Whh, bih, bhh, hk + (size_t)n1 * 32);
        gru_edges<4, true><<<(n4 + 255) / 256, 256, 0, stream>>>(
            idx4, n4, G, h, Wih, Whh, bih, bhh, hk + (size_t)n1 * 64);
    } else {
        gru_edges<2, false><<<(n2 + 255) / 256, 256, 0, stream>>>(
            idx2, n2, G, h, Wih, Whh, bih, bhh, hk);
        gru_edges<3, false><<<(n3 + 255) / 256, 256, 0, stream>>>(
            idx3, n3, G, h, Wih, Whh, bih, bhh, hk + (size_t)n1 * 32);
        gru_edges<4, false><<<(n4 + 255) / 256, 256, 0, stream>>>(
            idx4, n4, G, h, Wih, Whh, bih, bhh, hk + (size_t)n1 * 64);
    }

    mlp_out<<<blocksN1, 256, 0, stream>>>(h, hk, n1, W1, b1, W2, b2, out);
}

// Round 2
// 7200.800 us; speedup vs baseline: 1.0001x; 1.0001x over previous
//
#include <hip/hip_runtime.h>
#include <hip/hip_bf16.h>

#define UNITS 32

__device__ __forceinline__ float sigmoidf_(float x) {
    return 1.0f / (1.0f + __expf(-x));
}
__device__ __forceinline__ float tanhf_(float x) {
    float e = __expf(2.0f * x);
    return 1.0f - 2.0f / (e + 1.0f);
}
__device__ __forceinline__ float f4c(const float4& v, int q) {
    return q == 0 ? v.x : q == 1 ? v.y : q == 2 ? v.z : v.w;
}

// ---------------------------------------------------------------------------
// Kernel 1: G[node, 0..95] = h[node] @ Wih.T + bih   (per-node input gates)
// ---------------------------------------------------------------------------
__global__ __launch_bounds__(256) void precompute_gi(
    const float* __restrict__ h, const float* __restrict__ Wih,
    const float* __restrict__ bih, float* __restrict__ G, int n1)
{
    int node = blockIdx.x * 256 + threadIdx.x;
    if (node >= n1) return;
    float x[32];
    const float4* hx = (const float4*)(h + (size_t)node * 32);
#pragma unroll
    for (int c = 0; c < 8; ++c) {
        float4 v = hx[c];
        x[c*4+0] = v.x; x[c*4+1] = v.y; x[c*4+2] = v.z; x[c*4+3] = v.w;
    }
    float* grow = G + (size_t)node * 96;
#pragma unroll
    for (int jb = 0; jb < 24; ++jb) {
        float acc[4];
#pragma unroll
        for (int q = 0; q < 4; ++q) {
            int j = jb * 4 + q;
            float a = bih[j];
#pragma unroll
            for (int i = 0; i < 32; ++i)
                a += x[i] * Wih[j * 32 + i];
            acc[q] = a;
        }
        *(float4*)(grow + jb * 4) = make_float4(acc[0], acc[1], acc[2], acc[3]);
    }
}

// ---------------------------------------------------------------------------
// CSR build kernels
// ---------------------------------------------------------------------------
__global__ __launch_bounds__(256) void hist_kernel(
    const int* __restrict__ flat_idx, int nI, int* __restrict__ count)
{
    int i = blockIdx.x * 256 + threadIdx.x;
    if (i < nI) atomicAdd(&count[flat_idx[i]], 1);
}

__global__ __launch_bounds__(256) void scan_block(
    const int* __restrict__ count, int* __restrict__ incl,
    int* __restrict__ bsums, int n)
{
    __shared__ int s[256];
    int i = blockIdx.x * 256 + threadIdx.x;
    int v = (i < n) ? count[i] : 0;
    s[threadIdx.x] = v;
    __syncthreads();
    for (int d = 1; d < 256; d <<= 1) {
        int t = (threadIdx.x >= d) ? s[threadIdx.x - d] : 0;
        __syncthreads();
        s[threadIdx.x] += t;
        __syncthreads();
    }
    if (i < n) incl[i] = s[threadIdx.x];
    if (threadIdx.x == 255) bsums[blockIdx.x] = s[255];
}

__global__ __launch_bounds__(1024) void scan_bsums(int* bsums, int nb)
{
    __shared__ int s[1024];
    int v = (threadIdx.x < nb) ? bsums[threadIdx.x] : 0;
    s[threadIdx.x] = v;
    __syncthreads();
    for (int d = 1; d < 1024; d <<= 1) {
        int t = (threadIdx.x >= d) ? s[threadIdx.x - d] : 0;
        __syncthreads();
        s[threadIdx.x] += t;
        __syncthreads();
    }
    if (threadIdx.x < nb) bsums[threadIdx.x] = s[threadIdx.x] - v; // exclusive
}

__global__ __launch_bounds__(256) void finalize_offs(
    const int* __restrict__ incl, const int* __restrict__ bsums,
    int* __restrict__ offs, int n)
{
    int i = blockIdx.x * 256 + threadIdx.x;
    if (i < n) offs[i + 1] = incl[i] + bsums[blockIdx.x];
    if (i == 0) offs[0] = 0;
}

__global__ __launch_bounds__(256) void fill_entries(
    const int* __restrict__ flat_idx, int nI,
    int* __restrict__ cursor, int* __restrict__ entries)
{
    int i = blockIdx.x * 256 + threadIdx.x;
    if (i >= nI) return;
    int n = flat_idx[i];
    int p = atomicAdd(&cursor[n], 1);
    entries[p] = i;
}

// ---------------------------------------------------------------------------
// Kernel 2: per-edge GRU (K steps) -> dense outs[e*K+t][32]  (no atomics)
// ---------------------------------------------------------------------------
template <int K>
__global__ __launch_bounds__(256) void gru_edges_store(
    const int* __restrict__ idx, int nE,
    const float* __restrict__ G,
    const float* __restrict__ Whh, const float* __restrict__ bhh,
    float* __restrict__ outs)
{
    int e = blockIdx.x * 256 + threadIdx.x;
    if (e >= nE) return;

    float hv[32];
#pragma unroll
    for (int t = 0; t < K; ++t) {
        int node = idx[(size_t)e * K + t];
        const float* grow = G + (size_t)node * 96;

        float hn_[32];
#pragma unroll
        for (int jb = 0; jb < 8; ++jb) {
            float4 gr4 = *(const float4*)(grow + jb * 4);
            float4 gz4 = *(const float4*)(grow + 32 + jb * 4);
            float4 gn4 = *(const float4*)(grow + 64 + jb * 4);
#pragma unroll
            for (int q = 0; q < 4; ++q) {
                int j = jb * 4 + q;
                float ir = f4c(gr4, q), iz = f4c(gz4, q), in_ = f4c(gn4, q);
                float hr = bhh[j], hz = bhh[32 + j], hn2 = bhh[64 + j];
                if (t > 0) {
#pragma unroll
                    for (int i = 0; i < 32; ++i) {
                        hr  += hv[i] * Whh[j * 32 + i];
                        hz  += hv[i] * Whh[(32 + j) * 32 + i];
                        hn2 += hv[i] * Whh[(64 + j) * 32 + i];
                    }
                }
                float r = sigmoidf_(ir + hr);
                float z = sigmoidf_(iz + hz);
                float n = tanhf_(in_ + r * hn2);
                hn_[j] = (t > 0) ? ((1.0f - z) * n + z * hv[j]) : (1.0f - z) * n;
            }
        }
        float* dst = outs + ((size_t)e * K + t) * 32;
#pragma unroll
        for (int jb = 0; jb < 8; ++jb) {
            *(float4*)(dst + jb * 4) =
                make_float4(hn_[jb*4+0], hn_[jb*4+1], hn_[jb*4+2], hn_[jb*4+3]);
            hv[jb*4+0] = hn_[jb*4+0]; hv[jb*4+1] = hn_[jb*4+1];
            hv[jb*4+2] = hn_[jb*4+2]; hv[jb*4+3] = hn_[jb*4+3];
        }
    }
}

// ---------------------------------------------------------------------------
// Kernel 2b (fallback): atomic-scatter GRU (round-1 proven path)
// ---------------------------------------------------------------------------
template <int K, bool USE_G>
__global__ __launch_bounds__(256) void gru_edges_atomic(
    const int* __restrict__ idx, int nE,
    const float* __restrict__ G, const float* __restrict__ h,
    const float* __restrict__ Wih, const float* __restrict__ Whh,
    const float* __restrict__ bih, const float* __restrict__ bhh,
    float* __restrict__ hk)
{
    int e = blockIdx.x * 256 + threadIdx.x;
    if (e >= nE) return;

    float hv[32];
#pragma unroll
    for (int t = 0; t < K; ++t) {
        int node = idx[(size_t)e * K + t];
        const float* grow = G + (size_t)node * 96;

        float x[32];
        if (!USE_G) {
            const float4* hx = (const float4*)(h + (size_t)node * 32);
#pragma unroll
            for (int c = 0; c < 8; ++c) {
                float4 v = hx[c];
                x[c*4+0] = v.x; x[c*4+1] = v.y; x[c*4+2] = v.z; x[c*4+3] = v.w;
            }
        }

        float hn_[32];
#pragma unroll
        for (int jb = 0; jb < 8; ++jb) {
            float4 gr4, gz4, gn4;
            if (USE_G) {
                gr4 = *(const float4*)(grow + jb * 4);
                gz4 = *(const float4*)(grow + 32 + jb * 4);
                gn4 = *(const float4*)(grow + 64 + jb * 4);
            }
#pragma unroll
            for (int q = 0; q < 4; ++q) {
                int j = jb * 4 + q;
                float ir, iz, in_;
                if (USE_G) {
                    ir = f4c(gr4, q); iz = f4c(gz4, q); in_ = f4c(gn4, q);
                } else {
                    ir = bih[j]; iz = bih[32 + j]; in_ = bih[64 + j];
#pragma unroll
                    for (int i = 0; i < 32; ++i) {
                        ir  += x[i] * Wih[j * 32 + i];
                        iz  += x[i] * Wih[(32 + j) * 32 + i];
                        in_ += x[i] * Wih[(64 + j) * 32 + i];
                    }
                }
                float hr = bhh[j], hz = bhh[32 + j], hn2 = bhh[64 + j];
                if (t > 0) {
#pragma unroll
                    for (int i = 0; i < 32; ++i) {
                        hr  += hv[i] * Whh[j * 32 + i];
                        hz  += hv[i] * Whh[(32 + j) * 32 + i];
                        hn2 += hv[i] * Whh[(64 + j) * 32 + i];
                    }
                }
                float r = sigmoidf_(ir + hr);
                float z = sigmoidf_(iz + hz);
                float n = tanhf_(in_ + r * hn2);
                hn_[j] = (t > 0) ? ((1.0f - z) * n + z * hv[j]) : (1.0f - z) * n;
            }
        }
        float* dst = hk + (size_t)node * 32;
#pragma unroll
        for (int j = 0; j < 32; ++j) {
            hv[j] = hn_[j];
            atomicAdd(dst + j, hn_[j]);
        }
    }
}

// ---------------------------------------------------------------------------
// Kernel 3: segment gather: hk[seg] = sum over entries of outs row
//   8 threads per segment, float4 each -> 128B contiguous per entry
// ---------------------------------------------------------------------------
__global__ __launch_bounds__(256) void gather_hk(
    const int* __restrict__ offs, const int* __restrict__ entries,
    const float* __restrict__ outs, float* __restrict__ hk, int n1)
{
    int gid = blockIdx.x * 256 + threadIdx.x;
    int seg = gid >> 3;
    int sub = gid & 7;
    if (seg >= n1) return;
    int beg = offs[seg], end = offs[seg + 1];
    float4 acc = make_float4(0.f, 0.f, 0.f, 0.f);
    for (int p = beg; p < end; ++p) {
        int e = entries[p];
        float4 v = *(const float4*)(outs + (size_t)e * 32 + sub * 4);
        acc.x += v.x; acc.y += v.y; acc.z += v.z; acc.w += v.w;
    }
    *(float4*)(hk + (size_t)seg * 32 + sub * 4) = acc;
}

// ---------------------------------------------------------------------------
// Kernel 4: out = tanh([h|hk2|hk3|hk4] @ W1.T + b1) @ W2.T + b2
// ---------------------------------------------------------------------------
__global__ __launch_bounds__(256) void mlp_out(
    const float* __restrict__ h, const float* __restrict__ hk, int n1,
    const float* __restrict__ W1, const float* __restrict__ b1,
    const float* __restrict__ W2, const float* __restrict__ b2,
    float* __restrict__ out)
{
    int node = blockIdx.x * 256 + threadIdx.x;
    if (node >= n1) return;

    float acc[32];
#pragma unroll
    for (int j = 0; j < 32; ++j) acc[j] = b1[j];

    const float* zsrc[4];
    zsrc[0] = h + (size_t)node * 32;
    zsrc[1] = hk + (size_t)node * 32;
    zsrc[2] = hk + (size_t)n1 * 32 + (size_t)node * 32;
    zsrc[3] = hk + (size_t)n1 * 64 + (size_t)node * 32;

#pragma unroll
    for (int m = 0; m < 4; ++m) {
        float zc[32];
        const float4* zp = (const float4*)zsrc[m];
#pragma unroll
        for (int c = 0; c < 8; ++c) {
            float4 v = zp[c];
            zc[c*4+0] = v.x; zc[c*4+1] = v.y; zc[c*4+2] = v.z; zc[c*4+3] = v.w;
        }
#pragma unroll
        for (int j = 0; j < 32; ++j) {
#pragma unroll
            for (int i = 0; i < 32; ++i)
                acc[j] += zc[i] * W1[j * 128 + m * 32 + i];
        }
    }
    float tv[32];
#pragma unroll
    for (int j = 0; j < 32; ++j) tv[j] = tanhf_(acc[j]);

    float* orow = out + (size_t)node * 32;
#pragma unroll
    for (int ob = 0; ob < 8; ++ob) {
        float o[4];
#pragma unroll
        for (int q = 0; q < 4; ++q) {
            int oj = ob * 4 + q;
            float a = b2[oj];
#pragma unroll
            for (int j = 0; j < 32; ++j)
                a += tv[j] * W2[oj * 32 + j];
            o[q] = a;
        }
        *(float4*)(orow + ob * 4) = make_float4(o[0], o[1], o[2], o[3]);
    }
}

// ---------------------------------------------------------------------------
static inline size_t alignUp(size_t x, size_t a) { return (x + a - 1) & ~(a - 1); }

extern "C" void kernel_launch(void* const* d_in, const int* in_sizes, int n_in,
                              void* d_out, int out_size, void* d_ws, size_t ws_size,
                              hipStream_t stream)
{
    const float* h    = (const float*)d_in[0];
    const int*   idx2 = (const int*)d_in[1];
    const int*   idx3 = (const int*)d_in[2];
    const int*   idx4 = (const int*)d_in[3];
    const float* Wih  = (const float*)d_in[4];
    const float* Whh  = (const float*)d_in[5];
    const float* bih  = (const float*)d_in[6];
    const float* bhh  = (const float*)d_in[7];
    const float* W1   = (const float*)d_in[8];
    const float* b1   = (const float*)d_in[9];
    const float* W2   = (const float*)d_in[10];
    const float* b2   = (const float*)d_in[11];
    float* out = (float*)d_out;

    int n1 = in_sizes[0] / 32;
    int n2 = in_sizes[1] / 2;
    int n3 = in_sizes[2] / 3;
    int n4 = in_sizes[3] / 4;

    int maxI = n4 * 4;          // largest entry count (k=4)
    if (n3 * 3 > maxI) maxI = n3 * 3;
    if (n2 * 2 > maxI) maxI = n2 * 2;

    // ---- workspace layout (all aligned to 256B) ----
    size_t off = 0;
    size_t hkOff    = off; off = alignUp(off + (size_t)n1 * 96 * 4, 256);
    size_t gOff     = off; off = alignUp(off + (size_t)n1 * 96 * 4, 256);
    size_t outsOff  = off; off = alignUp(off + (size_t)maxI * 32 * 4, 256);
    size_t entOff   = off; off = alignUp(off + (size_t)maxI * 4, 256);
    size_t cntOff   = off; off = alignUp(off + (size_t)n1 * 4, 256);
    size_t inclOff  = off; off = alignUp(off + (size_t)n1 * 4, 256);
    size_t offsOff  = off; off = alignUp(off + ((size_t)n1 + 1) * 4, 256);
    size_t curOff   = off; off = alignUp(off + (size_t)n1 * 4, 256);
    size_t bsumOff  = off; off = alignUp(off + 4096, 256);
    size_t needGather = off;

    char* ws = (char*)d_ws;
    int blocksN1 = (n1 + 255) / 256;

    if (ws_size >= needGather) {
        // ===== gather path =====
        float* hk      = (float*)(ws + hkOff);
        float* G       = (float*)(ws + gOff);
        float* outs    = (float*)(ws + outsOff);
        int*   entries = (int*)(ws + entOff);
        int*   count   = (int*)(ws + cntOff);
        int*   incl    = (int*)(ws + inclOff);
        int*   offs    = (int*)(ws + offsOff);
        int*   cursor  = (int*)(ws + curOff);
        int*   bsums   = (int*)(ws + bsumOff);

        precompute_gi<<<blocksN1, 256, 0, stream>>>(h, Wih, bih, G, n1);

        const int* idxs[3] = { idx2, idx3, idx4 };
        int nEs[3] = { n2, n3, n4 };
        int Ks[3]  = { 2, 3, 4 };
        int nScanBlocks = (n1 + 255) / 256;

        for (int kk = 0; kk < 3; ++kk) {
            const int* idx = idxs[kk];
            int nE = nEs[kk], K = Ks[kk];
            int nI = nE * K;
            float* hkBase = hk + (size_t)n1 * 32 * kk;

            hipMemsetAsync(count, 0, (size_t)n1 * 4, stream);
            hist_kernel<<<(nI + 255) / 256, 256, 0, stream>>>(idx, nI, count);
            scan_block<<<nScanBlocks, 256, 0, stream>>>(count, incl, bsums, n1);
            scan_bsums<<<1, 1024, 0, stream>>>(bsums, nScanBlocks);
            finalize_offs<<<nScanBlocks, 256, 0, stream>>>(incl, bsums, offs, n1);
            hipMemcpyAsync(cursor, offs, (size_t)n1 * 4,
                           hipMemcpyDeviceToDevice, stream);
            fill_entries<<<(nI + 255) / 256, 256, 0, stream>>>(idx, nI, cursor, entries);

            if (K == 2)
                gru_edges_store<2><<<(nE + 255) / 256, 256, 0, stream>>>(
                    idx, nE, G, Whh, bhh, outs);
            else if (K == 3)
                gru_edges_store<3><<<(nE + 255) / 256, 256, 0, stream>>>(
                    idx, nE, G, Whh, bhh, outs);
            else
                gru_edges_store<4><<<(nE + 255) / 256, 256, 0, stream>>>(
                    idx, nE, G, Whh, bhh, outs);

            gather_hk<<<((n1 * 8) + 255) / 256, 256, 0, stream>>>(
                offs, entries, outs, hkBase, n1);
        }

        mlp_out<<<blocksN1, 256, 0, stream>>>(h, hk, n1, W1, b1, W2, b2, out);
        return;
    }

    // ===== fallback: round-1 atomic path =====
    float* hk = (float*)d_ws;
    size_t hkBytes = (size_t)n1 * 96 * sizeof(float);
    size_t gBytes  = (size_t)n1 * 96 * sizeof(float);
    bool useG = (ws_size >= hkBytes + gBytes);
    float* G = (float*)((char*)d_ws + hkBytes);

    hipMemsetAsync(d_ws, 0, hkBytes, stream);

    if (useG) {
        precompute_gi<<<blocksN1, 256, 0, stream>>>(h, Wih, bih, G, n1);
        gru_edges_atomic<2, true><<<(n2 + 255) / 256, 256, 0, stream>>>(
            idx2, n2, G, h, Wih, Whh, bih, bhh, hk);
        gru_edges_atomic<3, true><<<(n3 + 255) / 256, 256, 0, stream>>>(
            idx3, n3, G, h, Wih, Whh, bih, bhh, hk + (size_t)n1 * 32);
        gru_edges_atomic<4, true><<<(n4 + 255) / 256, 256, 0, stream>>>(
            idx4, n4, G, h, Wih, Whh, bih, bhh, hk + (size_t)n1 * 64);
    } else {
        gru_edges_atomic<2, false><<<(n2 + 255) / 256, 256, 0, stream>>>(
            idx2, n2, G, h, Wih, Whh, bih, bhh, hk);
        gru_edges_atomic<3, false><<<(n3 + 255) / 256, 256, 0, stream>>>(
            idx3, n3, G, h, Wih, Whh, bih, bhh, hk + (size_t)n1 * 32);
        gru_edges_atomic<4, false><<<(n4 + 255) / 256, 256, 0, stream>>>(
            idx4, n4, G, h, Wih, Whh, bih, bhh, hk + (size_t)n1 * 64);
    }

    mlp_out<<<blocksN1, 256, 0, stream>>>(h, hk, n1, W1, b1, W2, b2, out);
}